// Round 1
// baseline (97.663 us; speedup 1.0000x reference)
//
#include <hip/hip_runtime.h>

// DWT (Haar) forward: (16,4,1024,1024) f32 -> LL (16,4,512,512) ++ high (16,12,512,512)
//
// Layout facts:
//   in[n][c][y][x], strides (4*1024*1024, 1024*1024, 1024, 1)
//   d_out: LL flat first (16*4*512*512 = 16,777,216 floats),
//          then high[n][k][h][w] with k = [LH c0..3, HL c0..3, HH c0..3],
//          strides (12*512*512, 512*512, 512, 1), base offset 16,777,216.
//
// Each thread: one output row segment of 4 pixels (8 input cols x 2 input rows).
//   loads : 4x float4 (64 B), all 16B-aligned, consecutive threads cover
//           consecutive 32B input spans (full 128B lines consumed).
//   stores: 4x float4 (LL, LH, HL, HH), fully coalesced.

__global__ __launch_bounds__(256) void dwt_haar_fwd(const float* __restrict__ in,
                                                    float* __restrict__ out) {
    const int t = blockIdx.x * 256 + threadIdx.x;   // [0, 4*1024*1024)

    const int w4   = t & 127;        // output col group (4 cols), 128 per row
    const int rest = t >> 7;
    const int h    = rest & 511;     // output row
    const int nc   = rest >> 9;      // plane index n*4+c, [0,64)
    const int c    = nc & 3;
    const int n    = nc >> 2;

    // ---- input: rows 2h, 2h+1, cols 8*w4 .. 8*w4+7 ----
    const size_t inOff = (((size_t)nc * 1024 + 2 * h) * 1024) + 8 * (size_t)w4;
    const float4* in4 = reinterpret_cast<const float4*>(in + inOff);
    const float4 r0a = in4[0];
    const float4 r0b = in4[1];
    const float4 r1a = in4[256];     // +1024 floats = next input row
    const float4 r1b = in4[257];

    // ---- butterfly: per output pixel (a=even/even, b=even/odd, c=odd/even, d=odd/odd)
    float4 LL, LH, HL, HH;
    {
        // pixels 0,1 from r0a/r1a; pixels 2,3 from r0b/r1b
        const float s01_0 = r0a.x + r0a.y, d01_0 = r0a.x - r0a.y;
        const float s23_0 = r1a.x + r1a.y, d23_0 = r1a.x - r1a.y;
        const float s01_1 = r0a.z + r0a.w, d01_1 = r0a.z - r0a.w;
        const float s23_1 = r1a.z + r1a.w, d23_1 = r1a.z - r1a.w;
        const float s01_2 = r0b.x + r0b.y, d01_2 = r0b.x - r0b.y;
        const float s23_2 = r1b.x + r1b.y, d23_2 = r1b.x - r1b.y;
        const float s01_3 = r0b.z + r0b.w, d01_3 = r0b.z - r0b.w;
        const float s23_3 = r1b.z + r1b.w, d23_3 = r1b.z - r1b.w;

        LL.x = (s01_0 + s23_0) * 0.5f;  LH.x = (s01_0 - s23_0) * 0.5f;
        HL.x = (d01_0 + d23_0) * 0.5f;  HH.x = (d01_0 - d23_0) * 0.5f;
        LL.y = (s01_1 + s23_1) * 0.5f;  LH.y = (s01_1 - s23_1) * 0.5f;
        HL.y = (d01_1 + d23_1) * 0.5f;  HH.y = (d01_1 - d23_1) * 0.5f;
        LL.z = (s01_2 + s23_2) * 0.5f;  LH.z = (s01_2 - s23_2) * 0.5f;
        HL.z = (d01_2 + d23_2) * 0.5f;  HH.z = (d01_2 - d23_2) * 0.5f;
        LL.w = (s01_3 + s23_3) * 0.5f;  LH.w = (s01_3 - s23_3) * 0.5f;
        HL.w = (d01_3 + d23_3) * 0.5f;  HH.w = (d01_3 - d23_3) * 0.5f;
    }

    // ---- output addresses ----
    const size_t llOff = (((size_t)nc * 512 + h) * 512) + 4 * (size_t)w4;
    const size_t hiRow = (((size_t)(n * 12 + c) * 512 + h) * 512) + 4 * (size_t)w4
                         + (size_t)16777216;               // high starts after LL
    // HL is +4 channels, HH +8 channels: 4*512*512 = 1,048,576 floats apart
    *reinterpret_cast<float4*>(out + llOff)                 = LL;
    *reinterpret_cast<float4*>(out + hiRow)                 = LH;
    *reinterpret_cast<float4*>(out + hiRow + 1048576)       = HL;
    *reinterpret_cast<float4*>(out + hiRow + 2097152)       = HH;
}

extern "C" void kernel_launch(void* const* d_in, const int* in_sizes, int n_in,
                              void* d_out, int out_size, void* d_ws, size_t ws_size,
                              hipStream_t stream) {
    const float* in = (const float*)d_in[0];
    float* out = (float*)d_out;
    // 16*4*512*512 output pixels / 4 per thread = 4,194,304 threads
    const int threads = 256;
    const int blocks  = (16 * 4 * 512 * 512 / 4) / threads;   // 16384
    dwt_haar_fwd<<<blocks, threads, 0, stream>>>(in, out);
}